// Round 2
// baseline (372.810 us; speedup 1.0000x reference)
//
#include <hip/hip_runtime.h>
#include <stdint.h>

#define EPSV 1e-5f

typedef __attribute__((ext_vector_type(8))) short short8;
typedef __attribute__((ext_vector_type(4))) float floatx4;

__device__ __forceinline__ unsigned short f2bf(float f) {
    union { float f; uint32_t u; } v; v.f = f;
    uint32_t u = v.u;
    return (unsigned short)((u + 0x7FFFu + ((u >> 16) & 1u)) >> 16);  // RNE
}

// ---- kernel 0: fold BN2 into pointwise weights (fp32 -> bf16), build bias2 ----
__global__ __launch_bounds__(256) void k_fold(
        const float* __restrict__ pw_w, const float* __restrict__ pw_b,
        const float* __restrict__ g2, const float* __restrict__ b2,
        const float* __restrict__ m2, const float* __restrict__ v2,
        unsigned short* __restrict__ w_bf, float* __restrict__ bias2) {
    int idx = blockIdx.x * 256 + threadIdx.x;      // 32768 = 256*128
    int o = idx >> 7, c = idx & 127;
    float inv = g2[o] / sqrtf(v2[o] + EPSV);
    w_bf[idx] = f2bf(pw_w[idx] * inv);
    if (c == 0) bias2[o] = pw_b[o] * inv + b2[o] - m2[o] * inv;
}

// ---- kernel 1: depthwise 3x3 + BN1 + ReLU + exact fp32 prune, y -> bf16 [b][c][n] ----
__global__ __launch_bounds__(256) void k_dw(
        const float* __restrict__ x, const float* __restrict__ dw_w,
        const float* __restrict__ dw_b, const float* __restrict__ g1,
        const float* __restrict__ b1, const float* __restrict__ m1,
        const float* __restrict__ v1, unsigned short* __restrict__ y_ws) {
    const int c = blockIdx.x, b = blockIdx.y;
    const int t = threadIdx.x;
    __shared__ float halo[58 * 58];
    __shared__ float red[4];

    const float* xs = x + (size_t)(b * 128 + c) * 3136;
    for (int i = t; i < 3364; i += 256) {
        int r = i / 58, cc = i - r * 58;
        int gh = r - 1, gw = cc - 1;
        float v = 0.f;
        if ((unsigned)gh < 56u && (unsigned)gw < 56u) v = xs[gh * 56 + gw];
        halo[i] = v;
    }
    const float* wk = dw_w + c * 9;
    float k0 = wk[0], k1 = wk[1], k2 = wk[2], k3 = wk[3], k4 = wk[4],
          k5 = wk[5], k6 = wk[6], k7 = wk[7], k8 = wk[8];
    float inv1 = g1[c] / sqrtf(v1[c] + EPSV);                 // exact, matches ref
    float add0 = dw_b[c] * inv1 + b1[c] - m1[c] * inv1;
    __syncthreads();

    float yv[14];
    float mx = 0.f;
    #pragma unroll
    for (int i = 0; i < 7; ++i) {
        int base = i * 512 + 2 * t;        // pairs: base even, same row (56 even)
        if (base < 3136) {
            int h = base / 56, w = base - h * 56;
            const float* r0 = &halo[h * 58 + w];
            const float* r1 = r0 + 58;
            const float* r2 = r1 + 58;
            float a0 = r0[0], a1 = r0[1], a2 = r0[2], a3 = r0[3];
            float b0 = r1[0], b1_ = r1[1], b2_ = r1[2], b3 = r1[3];
            float c0 = r2[0], c1 = r2[1], c2 = r2[2], c3 = r2[3];
            float s0 = k0*a0 + k1*a1 + k2*a2 + k3*b0 + k4*b1_ + k5*b2_ + k6*c0 + k7*c1 + k8*c2;
            float s1 = k0*a1 + k1*a2 + k2*a3 + k3*b1_ + k4*b2_ + k5*b3 + k6*c1 + k7*c2 + k8*c3;
            float y0 = fmaxf(s0 * inv1 + add0, 0.f);
            float y1 = fmaxf(s1 * inv1 + add0, 0.f);
            mx = fmaxf(mx, fmaxf(y0, y1));
            yv[2 * i] = y0; yv[2 * i + 1] = y1;
        }
    }
    #pragma unroll
    for (int off = 32; off; off >>= 1) mx = fmaxf(mx, __shfl_xor(mx, off));
    if ((t & 63) == 0) red[t >> 6] = mx;
    __syncthreads();
    float m4 = fmaxf(fmaxf(red[0], red[1]), fmaxf(red[2], red[3]));
    float scale = (m4 >= 4.0f) ? 1.f : 0.f;   // DW_THR, exact fp32 decision

    uint32_t* yo = (uint32_t*)(y_ws + (size_t)(b * 128 + c) * 3136);
    #pragma unroll
    for (int i = 0; i < 7; ++i) {
        int base = i * 512 + 2 * t;
        if (base < 3136) {
            unsigned short h0 = f2bf(yv[2 * i] * scale);
            unsigned short h1 = f2bf(yv[2 * i + 1] * scale);
            yo[base >> 1] = (uint32_t)h0 | ((uint32_t)h1 << 16);
        }
    }
}

// ---- kernel 2: transpose y [b][c][n] -> y_t [b][n][c], 128c x 64n tiles ----
__global__ __launch_bounds__(256) void k_tr(
        const unsigned short* __restrict__ y,
        unsigned short* __restrict__ y_t) {
    const int nt = blockIdx.x;   // 49 tiles of 64 n (49*64 = 3136 exactly)
    const int b  = blockIdx.y;
    const int t  = threadIdx.x;
    __shared__ short s[128 * 65];   // stride 65 (odd) -> 2-way max conflicts (free)
    const int n0 = nt * 64;

    {   // load: 128 c-rows x 64 n, coalesced uint4, scatter u16 into padded LDS
        int row = t >> 3, chunk = t & 7;   // 32 rows x 8 chunks per iter
        #pragma unroll
        for (int i = 0; i < 4; ++i) {
            int c = row + i * 32;
            uint4 v = *(const uint4*)(y + (size_t)(b * 128 + c) * 3136 + n0 + chunk * 8);
            short* d = &s[c * 65 + chunk * 8];
            const short* sv = (const short*)&v;
            #pragma unroll
            for (int e = 0; e < 8; ++e) d[e] = sv[e];
        }
    }
    __syncthreads();
    {   // store: pack c-pairs, write y_t rows coalesced (256B per wave instr)
        #pragma unroll
        for (int i = 0; i < 16; ++i) {
            int idx = t + 256 * i;          // 4096 u32 outputs
            int n = idx >> 6, cp = idx & 63;
            uint32_t lo = (unsigned short)s[cp * 130 + n];
            uint32_t hi = (unsigned short)s[cp * 130 + 65 + n];
            *(uint32_t*)(y_t + ((size_t)b * 3136 + n0 + n) * 128 + cp * 2) = lo | (hi << 16);
        }
    }
}

// ---- kernel 3: pointwise GEMM via bf16 MFMA, fused bias + ReLU ----
// z[b,o,n] = relu( sum_c W[o,c] * y_t[b,n,c] + bias2[o] )   (PW prune skippable)
__global__ __launch_bounds__(256) void k_pw(
        const unsigned short* __restrict__ y_t,   // [b][n][c] bf16
        const unsigned short* __restrict__ w_bf,  // [o][c]    bf16
        const float* __restrict__ bias2, float* __restrict__ z) {
    const int nt = blockIdx.x;   // 25 N-tiles of 128 (last is half)
    const int mt = blockIdx.y;   // 2 M-tiles of 128
    const int b  = blockIdx.z;   // 64 batches
    const int t = threadIdx.x;
    const int SP = 136;          // padded row stride (shorts): 272B = 68 words -> uniform banks
    __shared__ __align__(16) short A_s[128 * 136];   // [o][c] k-contig
    __shared__ __align__(16) short B_s[128 * 136];   // [n][c] k-contig

    {
        int row = t >> 4, chunk = t & 15;   // 16 rows x 16 chunks per iter
        int n0 = nt * 128;
        #pragma unroll
        for (int i = 0; i < 8; ++i) {
            int r = row + i * 16;
            uint4 va = *(const uint4*)(w_bf + (size_t)(mt * 128 + r) * 128 + chunk * 8);
            *(uint4*)&A_s[r * SP + chunk * 8] = va;
            int n = n0 + r;
            uint4 vb = make_uint4(0, 0, 0, 0);
            if (n < 3136)
                vb = *(const uint4*)(y_t + (size_t)(b * 3136 + n) * 128 + chunk * 8);
            *(uint4*)&B_s[r * SP + chunk * 8] = vb;
        }
    }
    __syncthreads();

    const int wv = t >> 6, lane = t & 63;
    const int wm = wv >> 1, wn = wv & 1;     // 2x2 wave grid, 64x64 per wave
    const int q = lane >> 4, r = lane & 15;

    floatx4 acc[4][4];
    #pragma unroll
    for (int i = 0; i < 4; ++i)
        #pragma unroll
        for (int j = 0; j < 4; ++j) acc[i][j] = (floatx4)0.f;

    #pragma unroll
    for (int kk = 0; kk < 4; ++kk) {         // K = 128 = 4 x 32
        short8 a[4], bb[4];
        #pragma unroll
        for (int it = 0; it < 4; ++it)
            a[it] = *(const short8*)&A_s[(wm * 64 + it * 16 + r) * SP + kk * 32 + q * 8];
        #pragma unroll
        for (int jt = 0; jt < 4; ++jt)
            bb[jt] = *(const short8*)&B_s[(wn * 64 + jt * 16 + r) * SP + kk * 32 + q * 8];
        #pragma unroll
        for (int it = 0; it < 4; ++it)
            #pragma unroll
            for (int jt = 0; jt < 4; ++jt)
                acc[it][jt] = __builtin_amdgcn_mfma_f32_16x16x32_bf16(
                    a[it], bb[jt], acc[it][jt], 0, 0, 0);
    }

    const int n_base = nt * 128 + wn * 64;
    const int o_base = mt * 128 + wm * 64;
    float* zb = z + (size_t)b * 256 * 3136;
    #pragma unroll
    for (int it = 0; it < 4; ++it) {
        int o0 = o_base + it * 16 + q * 4;
        floatx4 bias = *(const floatx4*)(bias2 + o0);
        #pragma unroll
        for (int jt = 0; jt < 4; ++jt) {
            int n = n_base + jt * 16 + r;
            if (n < 3136) {
                #pragma unroll
                for (int j = 0; j < 4; ++j) {
                    float vz = fmaxf(acc[it][jt][j] + bias[j], 0.f);
                    zb[(size_t)(o0 + j) * 3136 + n] = vz;
                }
            }
        }
    }
}

extern "C" void kernel_launch(void* const* d_in, const int* in_sizes, int n_in,
                              void* d_out, int out_size, void* d_ws, size_t ws_size,
                              hipStream_t stream) {
    const float* x    = (const float*)d_in[0];
    const float* dw_w = (const float*)d_in[1];
    const float* dw_b = (const float*)d_in[2];
    const float* g1   = (const float*)d_in[3];
    const float* b1   = (const float*)d_in[4];
    const float* m1   = (const float*)d_in[5];
    const float* v1   = (const float*)d_in[6];
    const float* pw_w = (const float*)d_in[7];
    const float* pw_b = (const float*)d_in[8];
    const float* g2   = (const float*)d_in[9];
    const float* b2   = (const float*)d_in[10];
    const float* m2   = (const float*)d_in[11];
    const float* v2   = (const float*)d_in[12];
    float* z = (float*)d_out;

    // ws layout: y 51,380,224 B | y_t 51,380,224 B | w_bf 65,536 B | bias2 1,024 B
    const size_t YB = 51380224;
    unsigned short* y_ws = (unsigned short*)d_ws;
    unsigned short* y_t  = (unsigned short*)((char*)d_ws + YB);
    unsigned short* w_bf = (unsigned short*)((char*)d_ws + 2 * YB);
    float* bias2         = (float*)((char*)d_ws + 2 * YB + 65536);

    hipLaunchKernelGGL(k_fold, dim3(128), dim3(256), 0, stream,
                       pw_w, pw_b, g2, b2, m2, v2, w_bf, bias2);
    hipLaunchKernelGGL(k_dw, dim3(128, 64), dim3(256), 0, stream,
                       x, dw_w, dw_b, g1, b1, m1, v1, y_ws);
    hipLaunchKernelGGL(k_tr, dim3(49, 64), dim3(256), 0, stream,
                       y_ws, y_t);
    hipLaunchKernelGGL(k_pw, dim3(25, 2, 64), dim3(256), 0, stream,
                       y_t, w_bf, bias2, z);
}

// Round 3
// 359.034 us; speedup vs baseline: 1.0384x; 1.0384x over previous
//
#include <hip/hip_runtime.h>
#include <stdint.h>

#define EPSV 1e-5f

typedef __attribute__((ext_vector_type(8))) short short8;
typedef __attribute__((ext_vector_type(4))) float floatx4;

__device__ __forceinline__ unsigned short f2bf(float f) {
    union { float f; uint32_t u; } v; v.f = f;
    uint32_t u = v.u;
    return (unsigned short)((u + 0x7FFFu + ((u >> 16) & 1u)) >> 16);  // RNE
}

// ---- kernel 0: fold BN2 into pointwise weights (fp32 -> bf16), build bias2 ----
__global__ __launch_bounds__(256) void k_fold(
        const float* __restrict__ pw_w, const float* __restrict__ pw_b,
        const float* __restrict__ g2, const float* __restrict__ b2,
        const float* __restrict__ m2, const float* __restrict__ v2,
        unsigned short* __restrict__ w_bf, float* __restrict__ bias2) {
    int idx = blockIdx.x * 256 + threadIdx.x;      // 32768 = 256*128
    int o = idx >> 7, c = idx & 127;
    float inv = g2[o] / sqrtf(v2[o] + EPSV);
    w_bf[idx] = f2bf(pw_w[idx] * inv);
    if (c == 0) bias2[o] = pw_b[o] * inv + b2[o] - m2[o] * inv;
}

// ---- kernel 1: depthwise 3x3 + BN1 + ReLU + exact fp32 prune, y -> bf16 [b][c][n] ----
__global__ __launch_bounds__(256) void k_dw(
        const float* __restrict__ x, const float* __restrict__ dw_w,
        const float* __restrict__ dw_b, const float* __restrict__ g1,
        const float* __restrict__ b1, const float* __restrict__ m1,
        const float* __restrict__ v1, unsigned short* __restrict__ y_ws) {
    const int c = blockIdx.x, b = blockIdx.y;
    const int t = threadIdx.x;
    __shared__ float halo[58 * 58];
    __shared__ float red[4];

    const float* xs = x + (size_t)(b * 128 + c) * 3136;
    for (int i = t; i < 3364; i += 256) {
        int r = i / 58, cc = i - r * 58;
        int gh = r - 1, gw = cc - 1;
        float v = 0.f;
        if ((unsigned)gh < 56u && (unsigned)gw < 56u) v = xs[gh * 56 + gw];
        halo[i] = v;
    }
    const float* wk = dw_w + c * 9;
    float k0 = wk[0], k1 = wk[1], k2 = wk[2], k3 = wk[3], k4 = wk[4],
          k5 = wk[5], k6 = wk[6], k7 = wk[7], k8 = wk[8];
    float inv1 = g1[c] / sqrtf(v1[c] + EPSV);                 // exact, matches ref
    float add0 = dw_b[c] * inv1 + b1[c] - m1[c] * inv1;
    __syncthreads();

    float yv[14];
    float mx = 0.f;
    #pragma unroll
    for (int i = 0; i < 7; ++i) {
        int base = i * 512 + 2 * t;        // pairs: base even, same row (56 even)
        if (base < 3136) {
            int h = base / 56, w = base - h * 56;
            const float* r0 = &halo[h * 58 + w];
            const float* r1 = r0 + 58;
            const float* r2 = r1 + 58;
            float a0 = r0[0], a1 = r0[1], a2 = r0[2], a3 = r0[3];
            float b0 = r1[0], b1_ = r1[1], b2_ = r1[2], b3 = r1[3];
            float c0 = r2[0], c1 = r2[1], c2 = r2[2], c3 = r2[3];
            float s0 = k0*a0 + k1*a1 + k2*a2 + k3*b0 + k4*b1_ + k5*b2_ + k6*c0 + k7*c1 + k8*c2;
            float s1 = k0*a1 + k1*a2 + k2*a3 + k3*b1_ + k4*b2_ + k5*b3 + k6*c1 + k7*c2 + k8*c3;
            float y0 = fmaxf(s0 * inv1 + add0, 0.f);
            float y1 = fmaxf(s1 * inv1 + add0, 0.f);
            mx = fmaxf(mx, fmaxf(y0, y1));
            yv[2 * i] = y0; yv[2 * i + 1] = y1;
        }
    }
    #pragma unroll
    for (int off = 32; off; off >>= 1) mx = fmaxf(mx, __shfl_xor(mx, off));
    if ((t & 63) == 0) red[t >> 6] = mx;
    __syncthreads();
    float m4 = fmaxf(fmaxf(red[0], red[1]), fmaxf(red[2], red[3]));
    float scale = (m4 >= 4.0f) ? 1.f : 0.f;   // DW_THR, exact fp32 decision

    uint32_t* yo = (uint32_t*)(y_ws + (size_t)(b * 128 + c) * 3136);
    #pragma unroll
    for (int i = 0; i < 7; ++i) {
        int base = i * 512 + 2 * t;
        if (base < 3136) {
            unsigned short h0 = f2bf(yv[2 * i] * scale);
            unsigned short h1 = f2bf(yv[2 * i + 1] * scale);
            yo[base >> 1] = (uint32_t)h0 | ((uint32_t)h1 << 16);
        }
    }
}

// ---- kernel 2: pointwise GEMM, y read ONCE, in-LDS transpose via XOR swizzle ----
// z[b,o,n] = relu( sum_c W[o,c] * y[b,c,n] + bias2[o] )
// M=256 (all O, weights in registers), N=128 per block, K=128.
// B_s[n][c'] with c' = c ^ (((n>>3)&7)<<4): b128 frag reads bank-optimal,
// staging b16 writes ~8-way (hidden under HBM share).
__global__ __launch_bounds__(256, 2) void k_pw(
        const unsigned short* __restrict__ y,     // [b][c][3136] bf16
        const unsigned short* __restrict__ w_bf,  // [o][c]       bf16
        const float* __restrict__ bias2, float* __restrict__ z) {
    const int nt = blockIdx.x;   // 25 N-tiles of 128 (last is half)
    const int b  = blockIdx.y;   // 64 batches
    const int t = threadIdx.x;
    const int w = t >> 6, lane = t & 63;
    const int q = lane >> 4, r = lane & 15;
    __shared__ __align__(16) short B_s[128 * 128];   // 32 KB

    // A fragments in registers: wave w owns o in [w*64, w*64+64)
    short8 a[4][4];
    #pragma unroll
    for (int it = 0; it < 4; ++it)
        #pragma unroll
        for (int kk = 0; kk < 4; ++kk)
            a[it][kk] = *(const short8*)(w_bf +
                (size_t)(w * 64 + it * 16 + r) * 128 + kk * 32 + q * 8);

    // stage B: coalesced uint4 y loads, swizzled transpose into LDS
    {
        const int n0 = nt * 128;
        const int nch = (t & 15) * 8;          // local n chunk start
        const int sw = (t & 7) << 4;           // ((nch>>3)&7)<<4, lane-constant
        #pragma unroll
        for (int i = 0; i < 8; ++i) {
            int c = (t >> 4) + i * 16;
            int cp = c ^ sw;
            uint4 v = make_uint4(0, 0, 0, 0);
            if (n0 + nch < 3136)               // chunks are fully valid or fully out
                v = *(const uint4*)(y + (size_t)(b * 128 + c) * 3136 + n0 + nch);
            const short* sv = (const short*)&v;
            #pragma unroll
            for (int j = 0; j < 8; ++j)
                B_s[(nch + j) * 128 + cp] = sv[j];
        }
    }
    __syncthreads();

    floatx4 acc[4][8];
    #pragma unroll
    for (int i = 0; i < 4; ++i)
        #pragma unroll
        for (int j = 0; j < 8; ++j) acc[i][j] = (floatx4)0.f;

    #pragma unroll
    for (int kk = 0; kk < 4; ++kk) {           // K = 128 = 4 x 32
        short8 bb[8];
        #pragma unroll
        for (int jt = 0; jt < 8; ++jt) {
            int nl = jt * 16 + r;
            int cs = (kk * 32 + q * 8) ^ ((((nl >> 3) & 7)) << 4);
            bb[jt] = *(const short8*)&B_s[nl * 128 + cs];
        }
        #pragma unroll
        for (int it = 0; it < 4; ++it)
            #pragma unroll
            for (int jt = 0; jt < 8; ++jt)
                acc[it][jt] = __builtin_amdgcn_mfma_f32_16x16x32_bf16(
                    a[it][kk], bb[jt], acc[it][jt], 0, 0, 0);
    }

    const int n_base = nt * 128;
    float* zb = z + (size_t)b * 256 * 3136;
    #pragma unroll
    for (int it = 0; it < 4; ++it) {
        int o0 = w * 64 + it * 16 + q * 4;
        floatx4 bias = *(const floatx4*)(bias2 + o0);
        #pragma unroll
        for (int jt = 0; jt < 8; ++jt) {
            int n = n_base + jt * 16 + r;
            if (n < 3136) {
                #pragma unroll
                for (int j = 0; j < 4; ++j) {
                    float vz = fmaxf(acc[it][jt][j] + bias[j], 0.f);
                    zb[(size_t)(o0 + j) * 3136 + n] = vz;
                }
            }
        }
    }
}

extern "C" void kernel_launch(void* const* d_in, const int* in_sizes, int n_in,
                              void* d_out, int out_size, void* d_ws, size_t ws_size,
                              hipStream_t stream) {
    const float* x    = (const float*)d_in[0];
    const float* dw_w = (const float*)d_in[1];
    const float* dw_b = (const float*)d_in[2];
    const float* g1   = (const float*)d_in[3];
    const float* b1   = (const float*)d_in[4];
    const float* m1   = (const float*)d_in[5];
    const float* v1   = (const float*)d_in[6];
    const float* pw_w = (const float*)d_in[7];
    const float* pw_b = (const float*)d_in[8];
    const float* g2   = (const float*)d_in[9];
    const float* b2   = (const float*)d_in[10];
    const float* m2   = (const float*)d_in[11];
    const float* v2   = (const float*)d_in[12];
    float* z = (float*)d_out;

    // ws layout: y (bf16) 51,380,224 B | w_bf 65,536 B | bias2 1,024 B
    const size_t YB = 51380224;
    unsigned short* y_ws = (unsigned short*)d_ws;
    unsigned short* w_bf = (unsigned short*)((char*)d_ws + YB);
    float* bias2         = (float*)((char*)d_ws + YB + 65536);

    hipLaunchKernelGGL(k_fold, dim3(128), dim3(256), 0, stream,
                       pw_w, pw_b, g2, b2, m2, v2, w_bf, bias2);
    hipLaunchKernelGGL(k_dw, dim3(128, 64), dim3(256), 0, stream,
                       x, dw_w, dw_b, g1, b1, m1, v1, y_ws);
    hipLaunchKernelGGL(k_pw, dim3(25, 64), dim3(256), 0, stream,
                       y_ws, w_bf, bias2, z);
}

// Round 4
// 327.548 us; speedup vs baseline: 1.1382x; 1.0961x over previous
//
#include <hip/hip_runtime.h>
#include <stdint.h>

#define EPSV 1e-5f

typedef __attribute__((ext_vector_type(8))) short short8;
typedef __attribute__((ext_vector_type(4))) float floatx4;

__device__ __forceinline__ unsigned short f2bf(float f) {
    union { float f; uint32_t u; } v; v.f = f;
    uint32_t u = v.u;
    return (unsigned short)((u + 0x7FFFu + ((u >> 16) & 1u)) >> 16);  // RNE
}

// ---- kernel 1: depthwise 3x3 + BN1 + ReLU + exact fp32 prune -> y bf16 [b][c][n]
//      (b==0 blocks also fold BN2 into the pointwise weights: k_fold fused away)
__global__ __launch_bounds__(256) void k_dw(
        const float* __restrict__ x, const float* __restrict__ dw_w,
        const float* __restrict__ dw_b, const float* __restrict__ g1,
        const float* __restrict__ b1, const float* __restrict__ m1,
        const float* __restrict__ v1,
        const float* __restrict__ pw_w, const float* __restrict__ pw_b,
        const float* __restrict__ g2, const float* __restrict__ b2,
        const float* __restrict__ m2, const float* __restrict__ v2,
        unsigned short* __restrict__ y_ws,
        unsigned short* __restrict__ w_bf, float* __restrict__ bias2) {
    const int c = blockIdx.x, b = blockIdx.y;
    const int t = threadIdx.x;
    __shared__ float halo[58 * 58];
    __shared__ float red[4];

    if (b == 0) {   // fused weight-fold: 128 blocks x 256 threads = 32768 elems
        int idx = c * 256 + t;
        int o = idx >> 7, cc = idx & 127;
        float inv = g2[o] / sqrtf(v2[o] + EPSV);
        w_bf[idx] = f2bf(pw_w[idx] * inv);
        if (cc == 0) bias2[o] = pw_b[o] * inv + b2[o] - m2[o] * inv;
    }

    const float* xs = x + (size_t)(b * 128 + c) * 3136;
    // zero the 228 border cells of the 58x58 halo
    if (t < 228) {
        int pos;
        if (t < 58)       pos = t;                      // row 0
        else if (t < 116) pos = 57 * 58 + (t - 58);     // row 57
        else if (t < 172) pos = (t - 115) * 58;         // col 0, rows 1..56
        else              pos = (t - 171) * 58 + 57;    // col 57, rows 1..56
        halo[pos] = 0.f;
    }
    // interior: 784 float4 loads (rows are 56 wide; a float4 never crosses a row)
    {
        const floatx4* x4 = (const floatx4*)xs;
        #pragma unroll
        for (int i = 0; i < 4; ++i) {
            int f = t + 256 * i;
            if (f < 784) {
                floatx4 v = x4[f];
                int p = 4 * f;
                int h = p / 56, ww = p - h * 56;
                float* d = &halo[(h + 1) * 58 + ww + 1];
                d[0] = v[0]; d[1] = v[1]; d[2] = v[2]; d[3] = v[3];
            }
        }
    }
    const float* wk = dw_w + c * 9;
    float k0 = wk[0], k1 = wk[1], k2 = wk[2], k3 = wk[3], k4 = wk[4],
          k5 = wk[5], k6 = wk[6], k7 = wk[7], k8 = wk[8];
    float inv1 = g1[c] / sqrtf(v1[c] + EPSV);                 // exact, matches ref
    float add0 = dw_b[c] * inv1 + b1[c] - m1[c] * inv1;
    __syncthreads();

    float yv[14];
    float mx = 0.f;
    #pragma unroll
    for (int i = 0; i < 7; ++i) {
        int base = i * 512 + 2 * t;        // pairs: base even, same row (56 even)
        if (base < 3136) {
            int h = base / 56, w = base - h * 56;
            const float* r0 = &halo[h * 58 + w];
            const float* r1 = r0 + 58;
            const float* r2 = r1 + 58;
            float a0 = r0[0], a1 = r0[1], a2 = r0[2], a3 = r0[3];
            float b0 = r1[0], b1_ = r1[1], b2_ = r1[2], b3 = r1[3];
            float c0 = r2[0], c1 = r2[1], c2 = r2[2], c3 = r2[3];
            float s0 = k0*a0 + k1*a1 + k2*a2 + k3*b0 + k4*b1_ + k5*b2_ + k6*c0 + k7*c1 + k8*c2;
            float s1 = k0*a1 + k1*a2 + k2*a3 + k3*b1_ + k4*b2_ + k5*b3 + k6*c1 + k7*c2 + k8*c3;
            float y0 = fmaxf(s0 * inv1 + add0, 0.f);
            float y1 = fmaxf(s1 * inv1 + add0, 0.f);
            mx = fmaxf(mx, fmaxf(y0, y1));
            yv[2 * i] = y0; yv[2 * i + 1] = y1;
        }
    }
    #pragma unroll
    for (int off = 32; off; off >>= 1) mx = fmaxf(mx, __shfl_xor(mx, off));
    if ((t & 63) == 0) red[t >> 6] = mx;
    __syncthreads();
    float m4 = fmaxf(fmaxf(red[0], red[1]), fmaxf(red[2], red[3]));
    float scale = (m4 >= 4.0f) ? 1.f : 0.f;   // DW_THR, exact fp32 decision

    uint32_t* yo = (uint32_t*)(y_ws + (size_t)(b * 128 + c) * 3136);
    #pragma unroll
    for (int i = 0; i < 7; ++i) {
        int base = i * 512 + 2 * t;
        if (base < 3136) {
            unsigned short h0 = f2bf(yv[2 * i] * scale);
            unsigned short h1 = f2bf(yv[2 * i + 1] * scale);
            yo[base >> 1] = (uint32_t)h0 | ((uint32_t)h1 << 16);
        }
    }
}

// ---- kernel 2: pointwise GEMM, y read once, in-LDS transpose via XOR swizzle,
//      epilogue restaged through LDS -> contiguous dwordx4 nontemporal z stores
__global__ __launch_bounds__(256, 2) void k_pw(
        const unsigned short* __restrict__ y,     // [b][c][3136] bf16
        const unsigned short* __restrict__ w_bf,  // [o][c]       bf16
        const float* __restrict__ bias2, float* __restrict__ z) {
    const int nt = blockIdx.x;   // 25 N-tiles of 128 (last is half)
    const int b  = blockIdx.y;   // 64 batches
    const int t = threadIdx.x;
    const int w = t >> 6, lane = t & 63;
    const int q = lane >> 4, r = lane & 15;
    __shared__ __align__(16) char smem[33792];    // B_s (32 KB) then reused as E
    short* B_s = (short*)smem;                    // [n][c'] swizzled
    float* E   = (float*)smem;                    // [64][132] epilogue stage

    // A fragments in registers: wave w owns o in [w*64, w*64+64)
    short8 a[4][4];
    #pragma unroll
    for (int it = 0; it < 4; ++it)
        #pragma unroll
        for (int kk = 0; kk < 4; ++kk)
            a[it][kk] = *(const short8*)(w_bf +
                (size_t)(w * 64 + it * 16 + r) * 128 + kk * 32 + q * 8);

    // stage B: coalesced uint4 y loads, swizzled transpose into LDS
    {
        const int n0 = nt * 128;
        const int nch = (t & 15) * 8;          // local n chunk start
        const int sw = (t & 7) << 4;           // ((nch>>3)&7)<<4, lane-constant
        #pragma unroll
        for (int i = 0; i < 8; ++i) {
            int c = (t >> 4) + i * 16;
            int cp = c ^ sw;
            uint4 v = make_uint4(0, 0, 0, 0);
            if (n0 + nch < 3136)               // chunks fully valid or fully out
                v = *(const uint4*)(y + (size_t)(b * 128 + c) * 3136 + n0 + nch);
            const short* sv = (const short*)&v;
            #pragma unroll
            for (int j = 0; j < 8; ++j)
                B_s[(nch + j) * 128 + cp] = sv[j];
        }
    }
    __syncthreads();

    floatx4 acc[4][8];
    #pragma unroll
    for (int i = 0; i < 4; ++i)
        #pragma unroll
        for (int j = 0; j < 8; ++j) acc[i][j] = (floatx4)0.f;

    #pragma unroll
    for (int kk = 0; kk < 4; ++kk) {           // K = 128 = 4 x 32
        short8 bb[8];
        #pragma unroll
        for (int jt = 0; jt < 8; ++jt) {
            int nl = jt * 16 + r;
            int cs = (kk * 32 + q * 8) ^ ((((nl >> 3) & 7)) << 4);
            bb[jt] = *(const short8*)&B_s[nl * 128 + cs];
        }
        #pragma unroll
        for (int it = 0; it < 4; ++it)
            #pragma unroll
            for (int jt = 0; jt < 8; ++jt)
                acc[it][jt] = __builtin_amdgcn_mfma_f32_16x16x32_bf16(
                    a[it][kk], bb[jt], acc[it][jt], 0, 0, 0);
    }

    // epilogue: 4 chunks of 64 o-rows; bias+relu -> LDS -> dwordx4 nt stores
    const int n_base = nt * 128;
    float* zb = z + (size_t)b * 256 * 3136;
    #pragma unroll
    for (int it = 0; it < 4; ++it) {
        int o0 = w * 64 + it * 16 + q * 4;
        floatx4 bias = *(const floatx4*)(bias2 + o0);
        __syncthreads();                       // prior LDS readers done
        #pragma unroll
        for (int jt = 0; jt < 8; ++jt) {
            int n = jt * 16 + r;
            #pragma unroll
            for (int j = 0; j < 4; ++j)
                E[(w * 16 + q * 4 + j) * 132 + n] =
                    fmaxf(acc[it][jt][j] + bias[j], 0.f);
        }
        __syncthreads();
        #pragma unroll
        for (int s = 0; s < 8; ++s) {
            int idx = t + 256 * s;
            int rho = idx >> 5, n4 = (idx & 31) * 4;
            if (n_base + n4 < 3136) {
                floatx4 v = *(const floatx4*)&E[rho * 132 + n4];
                int o = (rho >> 4) * 64 + it * 16 + (rho & 15);
                __builtin_nontemporal_store(v,
                    (floatx4*)(zb + (size_t)o * 3136 + n_base + n4));
            }
        }
    }
}

extern "C" void kernel_launch(void* const* d_in, const int* in_sizes, int n_in,
                              void* d_out, int out_size, void* d_ws, size_t ws_size,
                              hipStream_t stream) {
    const float* x    = (const float*)d_in[0];
    const float* dw_w = (const float*)d_in[1];
    const float* dw_b = (const float*)d_in[2];
    const float* g1   = (const float*)d_in[3];
    const float* b1   = (const float*)d_in[4];
    const float* m1   = (const float*)d_in[5];
    const float* v1   = (const float*)d_in[6];
    const float* pw_w = (const float*)d_in[7];
    const float* pw_b = (const float*)d_in[8];
    const float* g2   = (const float*)d_in[9];
    const float* b2   = (const float*)d_in[10];
    const float* m2   = (const float*)d_in[11];
    const float* v2   = (const float*)d_in[12];
    float* z = (float*)d_out;

    // ws layout: y (bf16) 51,380,224 B | w_bf 65,536 B | bias2 1,024 B
    const size_t YB = 51380224;
    unsigned short* y_ws = (unsigned short*)d_ws;
    unsigned short* w_bf = (unsigned short*)((char*)d_ws + YB);
    float* bias2         = (float*)((char*)d_ws + YB + 65536);

    hipLaunchKernelGGL(k_dw, dim3(128, 64), dim3(256), 0, stream,
                       x, dw_w, dw_b, g1, b1, m1, v1,
                       pw_w, pw_b, g2, b2, m2, v2, y_ws, w_bf, bias2);
    hipLaunchKernelGGL(k_pw, dim3(25, 64), dim3(256), 0, stream,
                       y_ws, w_bf, bias2, z);
}